// Round 12
// baseline (217.094 us; speedup 1.0000x reference)
//
#include <hip/hip_runtime.h>

#define BB 4
#define C 256
#define HW 2304          // N = 48*48
#define NH 8
#define KD 32
#define D 128
#define DH 1024
#define MQ 256           // NH*KD

typedef unsigned short bf16u;
typedef __attribute__((ext_vector_type(8))) short short8;   // 8 bf16 (MFMA K=32 A/B frag)
typedef __attribute__((ext_vector_type(4))) short bfx4;     // 4 bf16 (8B)
typedef __attribute__((ext_vector_type(4))) float f32x4;    // MFMA C/D frag
typedef __attribute__((ext_vector_type(4))) unsigned ux4;
typedef __attribute__((ext_vector_type(2))) unsigned ux2;

union U8 { ux4 u; short8 s; };

__device__ __forceinline__ bf16u f2b(float f) {            // RNE
    unsigned u = __float_as_uint(f);
    return (bf16u)((u + 0x7fffu + ((u >> 16) & 1u)) >> 16);
}
// pack two fp32 -> dword of two bf16 (round-half-up): lo=a, hi=b. 3 VALU.
__device__ __forceinline__ unsigned pkb(float a, float b) {
    return __builtin_amdgcn_perm(__float_as_uint(b) + 0x8000u,
                                 __float_as_uint(a) + 0x8000u, 0x07060302u);
}

// async global->LDS, 16B/lane; lds base wave-uniform, dest = base + lane*16B
__device__ __forceinline__ void glds16(const bf16u* g, bf16u* l) {
    __builtin_amdgcn_global_load_lds(
        (const __attribute__((address_space(1))) unsigned int*)g,
        (__attribute__((address_space(3))) unsigned int*)l,
        16, 0, 0);
}

#define MFMA32 __builtin_amdgcn_mfma_f32_16x16x32_bf16

// ---------------------------------------------------------------------------
// Kernel 1: prepx — fused prep (QKV weights -> bf16 pre-tiled, BN folded,
// Q gets log2e; biasc) + xtrans (x [b][C][N] f32 -> xT [b][N][C] bf16).
// grid 769: blk<193 = prep, else xtrans.
// ---------------------------------------------------------------------------
__global__ __launch_bounds__(256) void prepx(
    const float* __restrict__ wq, const float* __restrict__ wk, const float* __restrict__ wv,
    const float* __restrict__ gq, const float* __restrict__ bq,
    const float* __restrict__ gk, const float* __restrict__ bk,
    const float* __restrict__ gv, const float* __restrict__ bv,
    const float* __restrict__ x,
    bf16u* __restrict__ WcT, float* __restrict__ biasc, bf16u* __restrict__ xT)
{
    __shared__ float tile[64][68];
    const float rs = rsqrtf(1.0f + 1e-5f);
    const float L2E = 1.4426950408889634f;
    const int t = threadIdx.x, blk = blockIdx.x;
    if (blk < 192) {
        const int idx = (blk*256 + t) * 8;
        const int row = idx >> 8;
        const int k   = idx & 255;
        const float* src; float sc;
        if (row < 256)      { src = wq + idx;            sc = gq[row]*rs*L2E; }
        else if (row < 512) { src = wk + (idx - 65536);  sc = gk[row-256]*rs; }
        else                { src = wv + (idx - 131072); sc = gv[row-512]*rs; }
        float4 a = *(const float4*)(src);
        float4 c = *(const float4*)(src + 4);
        ux4 v;
        v.x = pkb(a.x*sc, a.y*sc); v.y = pkb(a.z*sc, a.w*sc);
        v.z = pkb(c.x*sc, c.y*sc); v.w = pkb(c.z*sc, c.w*sc);
        const size_t dst = (size_t)((row>>7)*8 + (k>>5))*4096
                         + (size_t)((row&127)*4 + ((k&31)>>3))*8;
        *(ux4*)(WcT + dst) = v;
    } else if (blk == 192) {
        #pragma unroll
        for (int kk = 0; kk < 6; ++kk) {
            const int r = kk*256 + t;
            float v;
            if (r < 256)      v = bq[r] * L2E;
            else if (r < 512) v = bk[r - 256];
            else              v = bv[r - 512];
            biasc[r] = v;
        }
    } else {
        const int idx = blk - 193;                  // 576 xtrans blocks
        const int c0 = (idx & 3) * 64, n0 = ((idx >> 2) % 36) * 64, b = idx / 144;
        const float* xb = x + (size_t)b * C * HW;
        #pragma unroll
        for (int rr = 0; rr < 4; ++rr) {
            const int cl = rr*16 + (t >> 4);
            float4 v = *(const float4*)(xb + (size_t)(c0 + cl) * HW + n0 + (t & 15)*4);
            tile[cl][(t&15)*4+0] = v.x; tile[cl][(t&15)*4+1] = v.y;
            tile[cl][(t&15)*4+2] = v.z; tile[cl][(t&15)*4+3] = v.w;
        }
        __syncthreads();
        const int nl = t >> 2, ch = t & 3;
        short8 v0, v1;
        #pragma unroll
        for (int kk = 0; kk < 8; ++kk) v0[kk] = (short)f2b(tile[ch*16+kk][nl]);
        #pragma unroll
        for (int kk = 0; kk < 8; ++kk) v1[kk] = (short)f2b(tile[ch*16+8+kk][nl]);
        bf16u* dst = xT + ((size_t)b*HW + n0 + nl) * C + c0 + ch*16;
        *(short8*)(dst)     = v0;
        *(short8*)(dst + 8) = v1;
    }
}

// ---------------------------------------------------------------------------
// Kernel 2: QKV projection (R11, verified). A = pre-tiled bf16 weights,
// B = xT, both glds. 128x128, BK=32, triple-buffer prefetch-2, dense
// transposed epilogue; V written pi-permuted. grid (12,18,4), LDS 48KB.
// ---------------------------------------------------------------------------
__global__ __launch_bounds__(256, 3) void qkv_gemm(
    const bf16u* __restrict__ WcT, const float* __restrict__ biasc,
    const bf16u* __restrict__ xT,
    bf16u* __restrict__ qT, bf16u* __restrict__ kT, bf16u* __restrict__ vO)
{
    const int mt = blockIdx.x, ntb = blockIdx.y, b = blockIdx.z;
    const int r0 = mt * 128, c0 = ntb * 128;
    const int t = threadIdx.x, w = t >> 6, l = t & 63;
    const int l15 = l & 15, q = l >> 4;
    const int wr = w >> 1, wc = w & 1;

    __shared__ bf16u smem[24576];   // As: 0/4096/8192 | Bs: 12288/16384/20480

    const bf16u* xb = xT + (size_t)b * HW * C;

    const int sA0 = w*128 + l, sA1 = w*128 + 64 + l;        // 512 slots
    const bf16u* gA0 = WcT + (size_t)mt*32768 + (size_t)sA0*8;
    const bf16u* gA1 = WcT + (size_t)mt*32768 + (size_t)sA1*8;
    const bf16u* gB0 = xb + (size_t)(c0 + (sA0>>2)) * C + (sA0&3)*8;
    const bf16u* gB1 = xb + (size_t)(c0 + (sA1>>2)) * C + (sA1&3)*8;

    f32x4 acc[4][4];
    #pragma unroll
    for (int i = 0; i < 4; ++i)
        #pragma unroll
        for (int j = 0; j < 4; ++j) { acc[i][j][0]=0.f; acc[i][j][1]=0.f; acc[i][j][2]=0.f; acc[i][j][3]=0.f; }

    auto stage = [&](int it2, int bb) {
        bf16u* As = smem + bb*4096;
        bf16u* Bs = smem + 12288 + bb*4096;
        glds16(gA0 + it2*4096, As + sA0*8);
        glds16(gA1 + it2*4096, As + sA1*8);
        glds16(gB0 + it2*32,   Bs + sA0*8);
        glds16(gB1 + it2*32,   Bs + sA1*8);
    };

    const bool isV = (r0 >= 512);
    stage(0, 0); stage(1, 1);
    for (int it = 0; it < 8; ++it) {
        __syncthreads();
        if (it + 2 < 8) stage(it + 2, (it + 2) % 3);
        const bf16u* A = smem + (it % 3) * 4096;
        const bf16u* B = smem + 12288 + (it % 3) * 4096;
        short8 af[4], bf[4];
        #pragma unroll
        for (int i = 0; i < 4; ++i) af[i] = *(const short8*)(A + (wr*64 + i*16 + l15)*32 + q*8);
        #pragma unroll
        for (int j = 0; j < 4; ++j) bf[j] = *(const short8*)(B + (wc*64 + j*16 + l15)*32 + q*8);
        if (!isV) {
            #pragma unroll
            for (int i = 0; i < 4; ++i)
                #pragma unroll
                for (int j = 0; j < 4; ++j)
                    acc[i][j] = MFMA32(af[i], bf[j], acc[i][j], 0, 0, 0);
        } else {   // C^T: D[row=n][col=oc]
            #pragma unroll
            for (int i = 0; i < 4; ++i)
                #pragma unroll
                for (int j = 0; j < 4; ++j)
                    acc[i][j] = MFMA32(bf[j], af[i], acc[i][j], 0, 0, 0);
        }
    }

    __syncthreads();
    bf16u* Od = smem + w * 4608;          // per-wave [64][72]

    if (!isV) {
        float bC[4][4];
        #pragma unroll
        for (int i = 0; i < 4; ++i)
            #pragma unroll
            for (int r = 0; r < 4; ++r)
                bC[i][r] = biasc[r0 + wr*64 + i*16 + q*4 + r];
        #pragma unroll
        for (int i = 0; i < 4; ++i)
            #pragma unroll
            for (int j = 0; j < 4; ++j) {
                float y0 = acc[i][j][0] + bC[i][0];
                float y1 = acc[i][j][1] + bC[i][1];
                float y2 = acc[i][j][2] + bC[i][2];
                float y3 = acc[i][j][3] + bC[i][3];
                ux2 pk; pk.x = pkb(y0, y1); pk.y = pkb(y2, y3);
                *(ux2*)(Od + (j*16 + l15)*72 + i*16 + q*4) = pk;
            }
        bf16u* dst = (r0 < 256) ? qT : kT;
        #pragma unroll
        for (int hh = 0; hh < 2; ++hh) {
            const int h = ((r0 & 255) + wr*64 + hh*32) >> 5;
            bf16u* dh_ = dst + (size_t)(b*NH + h) * HW * KD;
            #pragma unroll
            for (int rg = 0; rg < 4; ++rg) {
                const int row = rg*16 + (l >> 2);
                const int n = c0 + wc*64 + row;
                short8 v = *(const short8*)(Od + row*72 + hh*32 + (l & 3)*8);
                *(short8*)(dh_ + (size_t)n * KD + (l & 3)*8) = v;
            }
        }
    } else {
        float bC[4];
        #pragma unroll
        for (int i = 0; i < 4; ++i)
            bC[i] = biasc[r0 + wr*64 + i*16 + l15];
        #pragma unroll
        for (int i = 0; i < 4; ++i)
            #pragma unroll
            for (int j = 0; j < 4; ++j) {
                float y0 = acc[i][j][0] + bC[i];
                float y1 = acc[i][j][1] + bC[i];
                float y2 = acc[i][j][2] + bC[i];
                float y3 = acc[i][j][3] + bC[i];
                ux2 pk; pk.x = pkb(y0, y1); pk.y = pkb(y2, y3);
                const int p = (j >> 1)*32 + q*8 + (j & 1)*4;
                *(ux2*)(Od + (i*16 + l15)*72 + p) = pk;
            }
        bf16u* dst = vO + (size_t)b * DH * HW;
        #pragma unroll
        for (int it2 = 0; it2 < 8; ++it2) {
            const int row = it2*8 + (l >> 3);
            const int d = (r0 - 512) + wr*64 + row;
            short8 v = *(const short8*)(Od + row*72 + (l & 7)*8);
            *(short8*)(dst + (size_t)d * HW + c0 + wc*64 + (l & 7)*8) = v;
        }
    }
}

// ---------------------------------------------------------------------------
// Kernel 3: MFMA flash attention, (qh x dh) wave split at R8 register cost.
// Block = 64 queries, 4 waves: wave (qh=w>>1, dh=w&1) computes
// O[qh*32..+32][dh*64..+64] -> o[2][4] = 32 acc VGPRs (R10's trap avoided).
// Grid (36,8,4) = 1152 blocks, LDS 32 KB -> 4-5 blocks/CU = ~18 waves/CU
// (2x R8's latency hiding; per-CU V-LDS-read volume unchanged ~26 us busy,
// now hidden). S^T/exp duplicated across the dh pair (VALU ~20 us/SIMD,
// still under the LDS pipe). K frags direct from global (register dbuf);
// V glds permuted+swizzled (conflict-free b128). Zero-movement P A-frags.
// No-max softmax (exp2, log2e pre-folded). Dense epilogue stores.
// ---------------------------------------------------------------------------
__global__ __launch_bounds__(256, 4) void attn_mfma(
    const bf16u* __restrict__ qT, const bf16u* __restrict__ kT,
    const bf16u* __restrict__ vg, bf16u* __restrict__ xg)
{
    const int nt = blockIdx.x, h = blockIdx.y, b = blockIdx.z;
    const int n0 = nt * 64;
    const int t = threadIdx.x;
    const int w = t >> 6, l = t & 63, l15 = l & 15, q = l >> 4;
    const int qh = w >> 1, dh = w & 1;

    const bf16u* qTh = qT + (size_t)(b*NH + h) * HW * KD;
    const bf16u* kTh = kT + (size_t)(b*NH + h) * HW * KD;
    const bf16u* vh  = vg + ((size_t)b*DH + (size_t)h*D) * HW;

    __shared__ bf16u smem[16384];   // Vs dbuf 2x8192 els = 32 KB

    short8 qf0 = *(const short8*)(qTh + (size_t)(n0 + qh*32 +      l15) * KD + q*8);
    short8 qf1 = *(const short8*)(qTh + (size_t)(n0 + qh*32 + 16 + l15) * KD + q*8);

    f32x4 o[2][4];
    #pragma unroll
    for (int a = 0; a < 2; ++a)
        #pragma unroll
        for (int d = 0; d < 4; ++d) { o[a][d][0]=0.f; o[a][d][1]=0.f; o[a][d][2]=0.f; o[a][d][3]=0.f; }
    float psum0 = 0.f, psum1 = 0.f;
    const f32x4 zero = {0.f, 0.f, 0.f, 0.f};

    auto stageV = [&](int m0, int bb) {
        bf16u* Vs = smem + bb*8192;
        #pragma unroll
        for (int j = 0; j < 4; ++j) {
            const int s = (w*4 + j)*64 + l;
            const int d = s >> 3, c = s & 7, cg = c ^ (d & 7);
            glds16(vh + (size_t)d*HW + m0 + cg*8, Vs + (w*4 + j)*512);
        }
    };

    // K frag register prefetch (tile 0) — same frags for all 4 waves
    short8 kfc[4], kfn[4];
    #pragma unroll
    for (int kt = 0; kt < 4; ++kt)
        kfc[kt] = *(const short8*)(kTh + (size_t)(kt*16 + l15) * KD + q*8);
    stageV(0, 0);

    for (int mt = 0; mt < 36; ++mt) {
        __syncthreads();
        if (mt < 35) {
            stageV((mt+1)*64, (mt+1)&1);
            #pragma unroll
            for (int kt = 0; kt < 4; ++kt)
                kfn[kt] = *(const short8*)(kTh + (size_t)((mt+1)*64 + kt*16 + l15) * KD + q*8);
        }
        const bf16u* Vs = smem + (mt&1)*8192;

        // --- S^T: lane holds S^T[m=kt*16+q*4+r][n=l15] (dup across dh) ---
        f32x4 st0[4], st1[4];
        #pragma unroll
        for (int kt = 0; kt < 4; ++kt) {
            st0[kt] = MFMA32(kfc[kt], qf0, zero, 0, 0, 0);
            st1[kt] = MFMA32(kfc[kt], qf1, zero, 0, 0, 0);
        }

        // --- P = exp2(S') (log2e folded); perm-pack; row partial sums ---
        unsigned dA0[4], dB0[4], dA1[4], dB1[4];
        #pragma unroll
        for (int kt = 0; kt < 4; ++kt) {
            float p0 = __builtin_amdgcn_exp2f(st0[kt][0]);
            float p1 = __builtin_amdgcn_exp2f(st0[kt][1]);
            float p2 = __builtin_amdgcn_exp2f(st0[kt][2]);
            float p3 = __builtin_amdgcn_exp2f(st0[kt][3]);
            psum0 += (p0 + p1) + (p2 + p3);
            dA0[kt] = pkb(p0, p1); dB0[kt] = pkb(p2, p3);
            float r0_ = __builtin_amdgcn_exp2f(st1[kt][0]);
            float r1_ = __builtin_amdgcn_exp2f(st1[kt][1]);
            float r2_ = __builtin_amdgcn_exp2f(st1[kt][2]);
            float r3_ = __builtin_amdgcn_exp2f(st1[kt][3]);
            psum1 += (r0_ + r1_) + (r2_ + r3_);
            dA1[kt] = pkb(r0_, r1_); dB1[kt] = pkb(r2_, r3_);
        }

        // --- PV: zero-movement A-frags; B = b128 from this wave's d-half ---
        #pragma unroll
        for (int kh = 0; kh < 2; ++kh) {
            U8 u0, u1;
            u0.u[0] = dA0[kh*2];   u0.u[1] = dB0[kh*2];
            u0.u[2] = dA0[kh*2+1]; u0.u[3] = dB0[kh*2+1];
            u1.u[0] = dA1[kh*2];   u1.u[1] = dB1[kh*2];
            u1.u[2] = dA1[kh*2+1]; u1.u[3] = dB1[kh*2+1];
            #pragma unroll
            for (int dt = 0; dt < 4; ++dt) {
                const int d = dh*64 + dt*16 + l15;
                short8 vf = *(const short8*)(Vs + d*64 + (((kh*4 + q) ^ (d & 7)) * 8));
                o[0][dt] = MFMA32(u0.s, vf, o[0][dt], 0, 0, 0);
                o[1][dt] = MFMA32(u1.s, vf, o[1][dt], 0, 0, 0);
            }
        }

        if (mt < 35) {
            #pragma unroll
            for (int kt = 0; kt < 4; ++kt) kfc[kt] = kfn[kt];
        }
    }

    // --- epilogue: sum reduce, /l + ReLU, LDS transpose, dense store ---
    psum0 += __shfl_xor(psum0, 16); psum0 += __shfl_xor(psum0, 32);
    psum1 += __shfl_xor(psum1, 16); psum1 += __shfl_xor(psum1, 32);
    float inv0[4], inv1[4];
    #pragma unroll
    for (int r = 0; r < 4; ++r) {
        inv0[r] = 1.0f / __shfl(psum0, q*4 + r);
        inv1[r] = 1.0f / __shfl(psum1, q*4 + r);
    }
    __syncthreads();
    bf16u* Od = smem + w * 2304;        // per-wave [32 q][72]
    #pragma unroll
    for (int dt = 0; dt < 4; ++dt)
        #pragma unroll
        for (int r = 0; r < 4; ++r) {
            float v0 = fmaxf(o[0][dt][r] * inv0[r], 0.f);
            float v1 = fmaxf(o[1][dt][r] * inv1[r], 0.f);
            Od[(     q*4 + r)*72 + dt*16 + l15] = f2b(v0);
            Od[(16 + q*4 + r)*72 + dt*16 + l15] = f2b(v1);
        }
    // dense: 8 lanes cover 128B (this wave's 64-d half) of one n row
    bf16u* xb = xg + ((size_t)b*HW + n0 + qh*32) * DH + h*D + dh*64;
    #pragma unroll
    for (int g = 0; g < 4; ++g) {
        const int row = g*8 + (l >> 3);
        *(short8*)(xb + (size_t)row*DH + (l & 7)*8) =
            *(const short8*)(Od + row*72 + (l & 7)*8);
    }
}

// ---------------------------------------------------------------------------
// Kernel 3.5: prep2 — wp fp32 -> bf16 (gp*rs folded), pre-tiled. grid 128.
// ---------------------------------------------------------------------------
__global__ __launch_bounds__(256) void prep2(
    const float* __restrict__ wp, const float* __restrict__ gp,
    bf16u* __restrict__ WpT)
{
    const float rs = rsqrtf(1.0f + 1e-5f);
    const int item = blockIdx.x*256 + threadIdx.x;
    const int row = item >> 7;
    const int k   = (item & 127) * 8;
    const float sc = gp[row] * rs;
    const float* src = wp + (size_t)row*DH + k;
    float4 a = *(const float4*)(src);
    float4 c = *(const float4*)(src + 4);
    ux4 v;
    v.x = pkb(a.x*sc, a.y*sc); v.y = pkb(a.z*sc, a.w*sc);
    v.z = pkb(c.x*sc, c.y*sc); v.w = pkb(c.z*sc, c.w*sc);
    const size_t dst = (size_t)((row>>6)*16 + (k>>6))*4096
                     + (size_t)((row&63)*8 + ((k&63)>>3))*8;
    *(ux4*)(WpT + dst) = v;
}

// ---------------------------------------------------------------------------
// Kernel 4: out = wp' @ xx + bp (R11, verified). 64x64, BK=64, triple-buffer
// prefetch-2, A/B linear glds. fp32 out. grid (4,36,4), LDS 48 KB.
// ---------------------------------------------------------------------------
__global__ __launch_bounds__(256, 3) void out_gemm(
    const bf16u* __restrict__ WpT, const float* __restrict__ bp,
    const bf16u* __restrict__ xx, float* __restrict__ out)
{
    const int mt = blockIdx.x, ntb = blockIdx.y, b = blockIdx.z;
    const int r0 = mt * 64, c0 = ntb * 64;
    const int t = threadIdx.x, w = t >> 6, l = t & 63;
    const int l15 = l & 15, q = l >> 4;
    const int wr = w >> 1, wc = w & 1;

    __shared__ bf16u smem[24576];

    const bf16u* xb = xx + (size_t)b * HW * DH;

    const int sA0 = t, sA1 = 256 + t;
    const bf16u* gA0 = WpT + (size_t)mt*65536 + (size_t)sA0*8;
    const bf16u* gA1 = WpT + (size_t)mt*65536 + (size_t)sA1*8;
    const int sB0 = w*128 + l, sB1 = w*128 + 64 + l;
    const bf16u* gB0 = xb + (size_t)(c0 + (sB0>>3)) * DH + (sB0&7)*8;
    const bf16u* gB1 = xb + (size_t)(c0 + (sB1>>3)) * DH + (sB1&7)*8;

    f32x4 acc[2][2];
    #pragma unroll
    for (int i = 0; i < 2; ++i)
        #pragma unroll
        for (int j = 0; j < 2; ++j) { acc[i][j][0]=0.f; acc[i][j][1]=0.f; acc[i][j][2]=0.f; acc[i][j][3]=0.f; }

    auto stage = [&](int it2, int bb) {
        bf16u* As = smem + bb*4096;
        bf16u* Bs = smem + 12288 + bb*4096;
        glds16(gA0 + it2*4096, As + sA0*8);
        glds16(gA1 + it2*4096, As + sA1*8);
        glds16(gB0 + it2*64,   Bs + sB0*8);
        glds16(gB1 + it2*64,   Bs + sB1*8);
    };

    stage(0, 0); stage(1, 1);
    for (int it = 0; it < 16; ++it) {
        __syncthreads();
        if (it + 2 < 16) stage(it + 2, (it + 2) % 3);
        const bf16u* A = smem + (it % 3) * 4096;
        const bf16u* B = smem + 12288 + (it % 3) * 4096;
        #pragma unroll
        for (int kk = 0; kk < 2; ++kk) {
            short8 af[2], bf[2];
            #pragma unroll
            for (int i = 0; i < 2; ++i) af[i] = *(const short8*)(A + (wr*32 + i*16 + l15)*64 + kk*32 + q*8);
            #pragma unroll
            for (int j = 0; j < 2; ++j) bf[j] = *(const short8*)(B + (wc*32 + j*16 + l15)*64 + kk*32 + q*8);
            #pragma unroll
            for (int i = 0; i < 2; ++i)
                #pragma unroll
                for (int j = 0; j < 2; ++j)
                    acc[i][j] = MFMA32(af[i], bf[j], acc[i][j], 0, 0, 0);
        }
    }

    #pragma unroll
    for (int i = 0; i < 2; ++i)
        #pragma unroll
        for (int r = 0; r < 4; ++r) {
            const int oc = r0 + wr*32 + i*16 + q*4 + r;
            const float bi = bp[oc];
            #pragma unroll
            for (int j = 0; j < 2; ++j) {
                const int n = c0 + wc*32 + j*16 + l15;
                out[((size_t)b*C + oc)*HW + n] = acc[i][j][r] + bi;
            }
        }
}

// ---------------------------------------------------------------------------
extern "C" void kernel_launch(void* const* d_in, const int* in_sizes, int n_in,
                              void* d_out, int out_size, void* d_ws, size_t ws_size,
                              hipStream_t stream) {
    const float* x  = (const float*)d_in[0];
    const float* wq = (const float*)d_in[1];
    const float* gq = (const float*)d_in[2];
    const float* bq = (const float*)d_in[3];
    const float* wk = (const float*)d_in[4];
    const float* gk = (const float*)d_in[5];
    const float* bk = (const float*)d_in[6];
    const float* wv = (const float*)d_in[7];
    const float* gv = (const float*)d_in[8];
    const float* bv = (const float*)d_in[9];
    const float* wp = (const float*)d_in[10];
    const float* gp = (const float*)d_in[11];
    const float* bp = (const float*)d_in[12];
    float* out = (float*)d_out;

    bf16u* qw = (bf16u*)d_ws;
    bf16u* kw = qw + (size_t)BB * MQ * HW;
    bf16u* vw = kw + (size_t)BB * MQ * HW;
    bf16u* xw = vw + (size_t)BB * DH * HW;
    bf16u* xTb = xw;
    bf16u* WcT = xw + (size_t)BB * MQ * HW;
    float* biasc = (float*)(WcT + 393216);
    bf16u* WpT = qw;                               // qT region, dead after attn

    hipLaunchKernelGGL(prepx, dim3(769), dim3(256), 0, stream,
                       wq, wk, wv, gq, bq, gk, bk, gv, bv, x, WcT, biasc, xTb);
    hipLaunchKernelGGL(qkv_gemm, dim3(12, 18, BB), dim3(256), 0, stream,
                       WcT, biasc, xTb, qw, kw, vw);
    hipLaunchKernelGGL(attn_mfma, dim3(36, NH, BB), dim3(256), 0, stream,
                       qw, kw, vw, xw);
    hipLaunchKernelGGL(prep2, dim3(128), dim3(256), 0, stream, wp, gp, WpT);
    hipLaunchKernelGGL(out_gemm, dim3(4, 36, BB), dim3(256), 0, stream,
                       WpT, bp, xw, out);
}

// Round 13
// 194.419 us; speedup vs baseline: 1.1166x; 1.1166x over previous
//
#include <hip/hip_runtime.h>

#define BB 4
#define C 256
#define HW 2304          // N = 48*48
#define NH 8
#define KD 32
#define D 128
#define DH 1024
#define MQ 256           // NH*KD

typedef unsigned short bf16u;
typedef __attribute__((ext_vector_type(8))) short short8;   // 8 bf16 (MFMA K=32 A/B frag)
typedef __attribute__((ext_vector_type(4))) short bfx4;     // 4 bf16 (8B)
typedef __attribute__((ext_vector_type(4))) float f32x4;    // MFMA C/D frag
typedef __attribute__((ext_vector_type(4))) unsigned ux4;
typedef __attribute__((ext_vector_type(2))) unsigned ux2;

union U8 { ux4 u; short8 s; };

__device__ __forceinline__ bf16u f2b(float f) {            // RNE
    unsigned u = __float_as_uint(f);
    return (bf16u)((u + 0x7fffu + ((u >> 16) & 1u)) >> 16);
}
// pack two fp32 -> dword of two bf16 (round-half-up): lo=a, hi=b. 3 VALU.
__device__ __forceinline__ unsigned pkb(float a, float b) {
    return __builtin_amdgcn_perm(__float_as_uint(b) + 0x8000u,
                                 __float_as_uint(a) + 0x8000u, 0x07060302u);
}

// async global->LDS, 16B/lane; lds base wave-uniform, dest = base + lane*16B
__device__ __forceinline__ void glds16(const bf16u* g, bf16u* l) {
    __builtin_amdgcn_global_load_lds(
        (const __attribute__((address_space(1))) unsigned int*)g,
        (__attribute__((address_space(3))) unsigned int*)l,
        16, 0, 0);
}

#define MFMA32 __builtin_amdgcn_mfma_f32_16x16x32_bf16

// ---------------------------------------------------------------------------
// Kernel 1: prepx — fused prep (QKV weights -> bf16 pre-tiled, BN folded,
// Q gets log2e; biasc) + xtrans (x [b][C][N] f32 -> xT [b][N][C] bf16).
// grid 769: blk<193 = prep, else xtrans.
// ---------------------------------------------------------------------------
__global__ __launch_bounds__(256) void prepx(
    const float* __restrict__ wq, const float* __restrict__ wk, const float* __restrict__ wv,
    const float* __restrict__ gq, const float* __restrict__ bq,
    const float* __restrict__ gk, const float* __restrict__ bk,
    const float* __restrict__ gv, const float* __restrict__ bv,
    const float* __restrict__ x,
    bf16u* __restrict__ WcT, float* __restrict__ biasc, bf16u* __restrict__ xT)
{
    __shared__ float tile[64][68];
    const float rs = rsqrtf(1.0f + 1e-5f);
    const float L2E = 1.4426950408889634f;
    const int t = threadIdx.x, blk = blockIdx.x;
    if (blk < 192) {
        const int idx = (blk*256 + t) * 8;
        const int row = idx >> 8;
        const int k   = idx & 255;
        const float* src; float sc;
        if (row < 256)      { src = wq + idx;            sc = gq[row]*rs*L2E; }
        else if (row < 512) { src = wk + (idx - 65536);  sc = gk[row-256]*rs; }
        else                { src = wv + (idx - 131072); sc = gv[row-512]*rs; }
        float4 a = *(const float4*)(src);
        float4 c = *(const float4*)(src + 4);
        ux4 v;
        v.x = pkb(a.x*sc, a.y*sc); v.y = pkb(a.z*sc, a.w*sc);
        v.z = pkb(c.x*sc, c.y*sc); v.w = pkb(c.z*sc, c.w*sc);
        const size_t dst = (size_t)((row>>7)*8 + (k>>5))*4096
                         + (size_t)((row&127)*4 + ((k&31)>>3))*8;
        *(ux4*)(WcT + dst) = v;
    } else if (blk == 192) {
        #pragma unroll
        for (int kk = 0; kk < 6; ++kk) {
            const int r = kk*256 + t;
            float v;
            if (r < 256)      v = bq[r] * L2E;
            else if (r < 512) v = bk[r - 256];
            else              v = bv[r - 512];
            biasc[r] = v;
        }
    } else {
        const int idx = blk - 193;                  // 576 xtrans blocks
        const int c0 = (idx & 3) * 64, n0 = ((idx >> 2) % 36) * 64, b = idx / 144;
        const float* xb = x + (size_t)b * C * HW;
        #pragma unroll
        for (int rr = 0; rr < 4; ++rr) {
            const int cl = rr*16 + (t >> 4);
            float4 v = *(const float4*)(xb + (size_t)(c0 + cl) * HW + n0 + (t & 15)*4);
            tile[cl][(t&15)*4+0] = v.x; tile[cl][(t&15)*4+1] = v.y;
            tile[cl][(t&15)*4+2] = v.z; tile[cl][(t&15)*4+3] = v.w;
        }
        __syncthreads();
        const int nl = t >> 2, ch = t & 3;
        short8 v0, v1;
        #pragma unroll
        for (int kk = 0; kk < 8; ++kk) v0[kk] = (short)f2b(tile[ch*16+kk][nl]);
        #pragma unroll
        for (int kk = 0; kk < 8; ++kk) v1[kk] = (short)f2b(tile[ch*16+8+kk][nl]);
        bf16u* dst = xT + ((size_t)b*HW + n0 + nl) * C + c0 + ch*16;
        *(short8*)(dst)     = v0;
        *(short8*)(dst + 8) = v1;
    }
}

// ---------------------------------------------------------------------------
// Kernel 2: QKV projection (R11, verified). A = pre-tiled bf16 weights,
// B = xT, both glds. 128x128, BK=32, triple-buffer prefetch-2, dense
// transposed epilogue; V written pi-permuted. grid (12,18,4), LDS 48KB.
// ---------------------------------------------------------------------------
__global__ __launch_bounds__(256, 3) void qkv_gemm(
    const bf16u* __restrict__ WcT, const float* __restrict__ biasc,
    const bf16u* __restrict__ xT,
    bf16u* __restrict__ qT, bf16u* __restrict__ kT, bf16u* __restrict__ vO)
{
    const int mt = blockIdx.x, ntb = blockIdx.y, b = blockIdx.z;
    const int r0 = mt * 128, c0 = ntb * 128;
    const int t = threadIdx.x, w = t >> 6, l = t & 63;
    const int l15 = l & 15, q = l >> 4;
    const int wr = w >> 1, wc = w & 1;

    __shared__ bf16u smem[24576];   // As: 0/4096/8192 | Bs: 12288/16384/20480

    const bf16u* xb = xT + (size_t)b * HW * C;

    const int sA0 = w*128 + l, sA1 = w*128 + 64 + l;        // 512 slots
    const bf16u* gA0 = WcT + (size_t)mt*32768 + (size_t)sA0*8;
    const bf16u* gA1 = WcT + (size_t)mt*32768 + (size_t)sA1*8;
    const bf16u* gB0 = xb + (size_t)(c0 + (sA0>>2)) * C + (sA0&3)*8;
    const bf16u* gB1 = xb + (size_t)(c0 + (sA1>>2)) * C + (sA1&3)*8;

    f32x4 acc[4][4];
    #pragma unroll
    for (int i = 0; i < 4; ++i)
        #pragma unroll
        for (int j = 0; j < 4; ++j) { acc[i][j][0]=0.f; acc[i][j][1]=0.f; acc[i][j][2]=0.f; acc[i][j][3]=0.f; }

    auto stage = [&](int it2, int bb) {
        bf16u* As = smem + bb*4096;
        bf16u* Bs = smem + 12288 + bb*4096;
        glds16(gA0 + it2*4096, As + sA0*8);
        glds16(gA1 + it2*4096, As + sA1*8);
        glds16(gB0 + it2*32,   Bs + sA0*8);
        glds16(gB1 + it2*32,   Bs + sA1*8);
    };

    const bool isV = (r0 >= 512);
    stage(0, 0); stage(1, 1);
    for (int it = 0; it < 8; ++it) {
        __syncthreads();
        if (it + 2 < 8) stage(it + 2, (it + 2) % 3);
        const bf16u* A = smem + (it % 3) * 4096;
        const bf16u* B = smem + 12288 + (it % 3) * 4096;
        short8 af[4], bf[4];
        #pragma unroll
        for (int i = 0; i < 4; ++i) af[i] = *(const short8*)(A + (wr*64 + i*16 + l15)*32 + q*8);
        #pragma unroll
        for (int j = 0; j < 4; ++j) bf[j] = *(const short8*)(B + (wc*64 + j*16 + l15)*32 + q*8);
        if (!isV) {
            #pragma unroll
            for (int i = 0; i < 4; ++i)
                #pragma unroll
                for (int j = 0; j < 4; ++j)
                    acc[i][j] = MFMA32(af[i], bf[j], acc[i][j], 0, 0, 0);
        } else {   // C^T: D[row=n][col=oc]
            #pragma unroll
            for (int i = 0; i < 4; ++i)
                #pragma unroll
                for (int j = 0; j < 4; ++j)
                    acc[i][j] = MFMA32(bf[j], af[i], acc[i][j], 0, 0, 0);
        }
    }

    __syncthreads();
    bf16u* Od = smem + w * 4608;          // per-wave [64][72]

    if (!isV) {
        float bC[4][4];
        #pragma unroll
        for (int i = 0; i < 4; ++i)
            #pragma unroll
            for (int r = 0; r < 4; ++r)
                bC[i][r] = biasc[r0 + wr*64 + i*16 + q*4 + r];
        #pragma unroll
        for (int i = 0; i < 4; ++i)
            #pragma unroll
            for (int j = 0; j < 4; ++j) {
                float y0 = acc[i][j][0] + bC[i][0];
                float y1 = acc[i][j][1] + bC[i][1];
                float y2 = acc[i][j][2] + bC[i][2];
                float y3 = acc[i][j][3] + bC[i][3];
                ux2 pk; pk.x = pkb(y0, y1); pk.y = pkb(y2, y3);
                *(ux2*)(Od + (j*16 + l15)*72 + i*16 + q*4) = pk;
            }
        bf16u* dst = (r0 < 256) ? qT : kT;
        #pragma unroll
        for (int hh = 0; hh < 2; ++hh) {
            const int h = ((r0 & 255) + wr*64 + hh*32) >> 5;
            bf16u* dh_ = dst + (size_t)(b*NH + h) * HW * KD;
            #pragma unroll
            for (int rg = 0; rg < 4; ++rg) {
                const int row = rg*16 + (l >> 2);
                const int n = c0 + wc*64 + row;
                short8 v = *(const short8*)(Od + row*72 + hh*32 + (l & 3)*8);
                *(short8*)(dh_ + (size_t)n * KD + (l & 3)*8) = v;
            }
        }
    } else {
        float bC[4];
        #pragma unroll
        for (int i = 0; i < 4; ++i)
            bC[i] = biasc[r0 + wr*64 + i*16 + l15];
        #pragma unroll
        for (int i = 0; i < 4; ++i)
            #pragma unroll
            for (int j = 0; j < 4; ++j) {
                float y0 = acc[i][j][0] + bC[i];
                float y1 = acc[i][j][1] + bC[i];
                float y2 = acc[i][j][2] + bC[i];
                float y3 = acc[i][j][3] + bC[i];
                ux2 pk; pk.x = pkb(y0, y1); pk.y = pkb(y2, y3);
                const int p = (j >> 1)*32 + q*8 + (j & 1)*4;
                *(ux2*)(Od + (i*16 + l15)*72 + p) = pk;
            }
        bf16u* dst = vO + (size_t)b * DH * HW;
        #pragma unroll
        for (int it2 = 0; it2 < 8; ++it2) {
            const int row = it2*8 + (l >> 3);
            const int d = (r0 - 512) + wr*64 + row;
            short8 v = *(const short8*)(Od + row*72 + (l & 7)*8);
            *(short8*)(dst + (size_t)d * HW + c0 + wc*64 + (l & 7)*8) = v;
        }
    }
}

// ---------------------------------------------------------------------------
// Kernel 3: MFMA flash attention — R11 structure (best measured: 82.2 us)
// + MFMA row-sums: l = P.ones via 4 extra MFMAs/wave-tile on the already-
// built P A-frags (ones is pi-invariant). Deletes 32 psum VALU adds/tile
// AND the epilogue shuffle-reduce (lane reg r holds query q*4+r's sum
// directly in C-layout). l now sums bf16-quantized P — consistent with
// the PV numerator. Block 256 = 4 waves x 32 queries (o[2][8]); K frags
// direct from global (register dbuf, coalesced, L2-resident); V glds
// permuted+swizzled (conflict-free b128); zero-movement P A-frags; no-max
// softmax (exp2, log2e pre-folded). grid (18,8,4). LDS 34.8KB.
// ---------------------------------------------------------------------------
__global__ __launch_bounds__(256, 3) void attn_mfma(
    const bf16u* __restrict__ qT, const bf16u* __restrict__ kT,
    const bf16u* __restrict__ vg, bf16u* __restrict__ xg)
{
    const int nt = blockIdx.x, h = blockIdx.y, b = blockIdx.z;
    const int n0 = nt * 128;
    const int t = threadIdx.x;
    const int w = t >> 6, l = t & 63, l15 = l & 15, q = l >> 4;

    const bf16u* qTh = qT + (size_t)(b*NH + h) * HW * KD;
    const bf16u* kTh = kT + (size_t)(b*NH + h) * HW * KD;
    const bf16u* vh  = vg + ((size_t)b*DH + (size_t)h*D) * HW;

    __shared__ bf16u smem[17408];   // Vs dbuf 2x8192 els (32KB); Od reuse

    short8 qf0 = *(const short8*)(qTh + (size_t)(n0 + w*32 +      l15) * KD + q*8);
    short8 qf1 = *(const short8*)(qTh + (size_t)(n0 + w*32 + 16 + l15) * KD + q*8);

    const short8 ones = { (short)0x3F80, (short)0x3F80, (short)0x3F80, (short)0x3F80,
                          (short)0x3F80, (short)0x3F80, (short)0x3F80, (short)0x3F80 };

    f32x4 o[2][8];
    #pragma unroll
    for (int a = 0; a < 2; ++a)
        #pragma unroll
        for (int d = 0; d < 8; ++d) { o[a][d][0]=0.f; o[a][d][1]=0.f; o[a][d][2]=0.f; o[a][d][3]=0.f; }
    f32x4 os0 = {0.f,0.f,0.f,0.f}, os1 = {0.f,0.f,0.f,0.f};   // MFMA row sums
    const f32x4 zero = {0.f, 0.f, 0.f, 0.f};

    auto stageV = [&](int m0, int bb) {
        bf16u* Vs = smem + bb*8192;
        #pragma unroll
        for (int j = 0; j < 4; ++j) {
            const int s = (w*4 + j)*64 + l;
            const int d = s >> 3, c = s & 7, cg = c ^ (d & 7);
            glds16(vh + (size_t)d*HW + m0 + cg*8, Vs + (w*4 + j)*512);
        }
    };

    // K frag register prefetch (tile 0)
    short8 kfc[4], kfn[4];
    #pragma unroll
    for (int kt = 0; kt < 4; ++kt)
        kfc[kt] = *(const short8*)(kTh + (size_t)(kt*16 + l15) * KD + q*8);
    stageV(0, 0);

    for (int mt = 0; mt < 36; ++mt) {
        __syncthreads();
        if (mt < 35) {
            stageV((mt+1)*64, (mt+1)&1);
            #pragma unroll
            for (int kt = 0; kt < 4; ++kt)
                kfn[kt] = *(const short8*)(kTh + (size_t)((mt+1)*64 + kt*16 + l15) * KD + q*8);
        }
        const bf16u* Vs = smem + (mt&1)*8192;

        // --- S^T: lane holds S^T[m=kt*16+q*4+r][n=l15] ---
        f32x4 st0[4], st1[4];
        #pragma unroll
        for (int kt = 0; kt < 4; ++kt) {
            st0[kt] = MFMA32(kfc[kt], qf0, zero, 0, 0, 0);
            st1[kt] = MFMA32(kfc[kt], qf1, zero, 0, 0, 0);
        }

        // --- P = exp2(S') (log2e folded); perm-pack (no VALU psum) ---
        unsigned dA0[4], dB0[4], dA1[4], dB1[4];
        #pragma unroll
        for (int kt = 0; kt < 4; ++kt) {
            float p0 = __builtin_amdgcn_exp2f(st0[kt][0]);
            float p1 = __builtin_amdgcn_exp2f(st0[kt][1]);
            float p2 = __builtin_amdgcn_exp2f(st0[kt][2]);
            float p3 = __builtin_amdgcn_exp2f(st0[kt][3]);
            dA0[kt] = pkb(p0, p1); dB0[kt] = pkb(p2, p3);
            float r0_ = __builtin_amdgcn_exp2f(st1[kt][0]);
            float r1_ = __builtin_amdgcn_exp2f(st1[kt][1]);
            float r2_ = __builtin_amdgcn_exp2f(st1[kt][2]);
            float r3_ = __builtin_amdgcn_exp2f(st1[kt][3]);
            dA1[kt] = pkb(r0_, r1_); dB1[kt] = pkb(r2_, r3_);
        }

        // --- PV + MFMA row-sums: zero-movement A-frags; B = b128 / ones ---
        #pragma unroll
        for (int kh = 0; kh < 2; ++kh) {
            U8 u0, u1;
            u0.u[0] = dA0[kh*2];   u0.u[1] = dB0[kh*2];
            u0.u[2] = dA0[kh*2+1]; u0.u[3] = dB0[kh*2+1];
            u1.u[0] = dA1[kh*2];   u1.u[1] = dB1[kh*2];
            u1.u[2] = dA1[kh*2+1]; u1.u[3] = dB1[kh*2+1];
            #pragma unroll
            for (int dt = 0; dt < 8; ++dt) {
                const int d = dt*16 + l15;
                short8 vf = *(const short8*)(Vs + d*64 + (((kh*4 + q) ^ (d & 7)) * 8));
                o[0][dt] = MFMA32(u0.s, vf, o[0][dt], 0, 0, 0);
                o[1][dt] = MFMA32(u1.s, vf, o[1][dt], 0, 0, 0);
            }
            os0 = MFMA32(u0.s, ones, os0, 0, 0, 0);
            os1 = MFMA32(u1.s, ones, os1, 0, 0, 0);
        }

        if (mt < 35) {
            #pragma unroll
            for (int kt = 0; kt < 4; ++kt) kfc[kt] = kfn[kt];
        }
    }

    // --- epilogue: /l + ReLU, LDS transpose, dense [n][DH] store ---
    float inv0[4], inv1[4];
    #pragma unroll
    for (int r = 0; r < 4; ++r) {
        inv0[r] = 1.0f / os0[r];      // lane reg r = sum for query q*4+r
        inv1[r] = 1.0f / os1[r];
    }
    __syncthreads();
    bf16u* Od = smem + w * 4352;        // per-wave [32][136]
    #pragma unroll
    for (int dt = 0; dt < 8; ++dt)
        #pragma unroll
        for (int r = 0; r < 4; ++r) {
            float v0 = fmaxf(o[0][dt][r] * inv0[r], 0.f);
            float v1 = fmaxf(o[1][dt][r] * inv1[r], 0.f);
            Od[(     q*4 + r)*136 + dt*16 + l15] = f2b(v0);
            Od[(16 + q*4 + r)*136 + dt*16 + l15] = f2b(v1);
        }
    // dense: 8 lanes cover 128B of one n row; 8 rows/instr; 8 instrs
    bf16u* xb = xg + ((size_t)b*HW + n0 + w*32) * DH + h*D;
    #pragma unroll
    for (int g = 0; g < 4; ++g) {
        const int row = g*8 + (l >> 3);
        #pragma unroll
        for (int hf = 0; hf < 2; ++hf) {
            const int ch = hf*8 + (l & 7);
            *(short8*)(xb + (size_t)row*DH + ch*8) =
                *(const short8*)(Od + row*136 + ch*8);
        }
    }
}

// ---------------------------------------------------------------------------
// Kernel 3.5: prep2 — wp fp32 -> bf16 (gp*rs folded), pre-tiled. grid 128.
// ---------------------------------------------------------------------------
__global__ __launch_bounds__(256) void prep2(
    const float* __restrict__ wp, const float* __restrict__ gp,
    bf16u* __restrict__ WpT)
{
    const float rs = rsqrtf(1.0f + 1e-5f);
    const int item = blockIdx.x*256 + threadIdx.x;
    const int row = item >> 7;
    const int k   = (item & 127) * 8;
    const float sc = gp[row] * rs;
    const float* src = wp + (size_t)row*DH + k;
    float4 a = *(const float4*)(src);
    float4 c = *(const float4*)(src + 4);
    ux4 v;
    v.x = pkb(a.x*sc, a.y*sc); v.y = pkb(a.z*sc, a.w*sc);
    v.z = pkb(c.x*sc, c.y*sc); v.w = pkb(c.z*sc, c.w*sc);
    const size_t dst = (size_t)((row>>6)*16 + (k>>6))*4096
                     + (size_t)((row&63)*8 + ((k&63)>>3))*8;
    *(ux4*)(WpT + dst) = v;
}

// ---------------------------------------------------------------------------
// Kernel 4: out = wp' @ xx + bp (R11, verified). 64x64, BK=64, triple-buffer
// prefetch-2, A/B linear glds. fp32 out. grid (4,36,4), LDS 48 KB.
// ---------------------------------------------------------------------------
__global__ __launch_bounds__(256, 3) void out_gemm(
    const bf16u* __restrict__ WpT, const float* __restrict__ bp,
    const bf16u* __restrict__ xx, float* __restrict__ out)
{
    const int mt = blockIdx.x, ntb = blockIdx.y, b = blockIdx.z;
    const int r0 = mt * 64, c0 = ntb * 64;
    const int t = threadIdx.x, w = t >> 6, l = t & 63;
    const int l15 = l & 15, q = l >> 4;
    const int wr = w >> 1, wc = w & 1;

    __shared__ bf16u smem[24576];

    const bf16u* xb = xx + (size_t)b * HW * DH;

    const int sA0 = t, sA1 = 256 + t;
    const bf16u* gA0 = WpT + (size_t)mt*65536 + (size_t)sA0*8;
    const bf16u* gA1 = WpT + (size_t)mt*65536 + (size_t)sA1*8;
    const int sB0 = w*128 + l, sB1 = w*128 + 64 + l;
    const bf16u* gB0 = xb + (size_t)(c0 + (sB0>>3)) * DH + (sB0&7)*8;
    const bf16u* gB1 = xb + (size_t)(c0 + (sB1>>3)) * DH + (sB1&7)*8;

    f32x4 acc[2][2];
    #pragma unroll
    for (int i = 0; i < 2; ++i)
        #pragma unroll
        for (int j = 0; j < 2; ++j) { acc[i][j][0]=0.f; acc[i][j][1]=0.f; acc[i][j][2]=0.f; acc[i][j][3]=0.f; }

    auto stage = [&](int it2, int bb) {
        bf16u* As = smem + bb*4096;
        bf16u* Bs = smem + 12288 + bb*4096;
        glds16(gA0 + it2*4096, As + sA0*8);
        glds16(gA1 + it2*4096, As + sA1*8);
        glds16(gB0 + it2*64,   Bs + sB0*8);
        glds16(gB1 + it2*64,   Bs + sB1*8);
    };

    stage(0, 0); stage(1, 1);
    for (int it = 0; it < 16; ++it) {
        __syncthreads();
        if (it + 2 < 16) stage(it + 2, (it + 2) % 3);
        const bf16u* A = smem + (it % 3) * 4096;
        const bf16u* B = smem + 12288 + (it % 3) * 4096;
        #pragma unroll
        for (int kk = 0; kk < 2; ++kk) {
            short8 af[2], bf[2];
            #pragma unroll
            for (int i = 0; i < 2; ++i) af[i] = *(const short8*)(A + (wr*32 + i*16 + l15)*64 + kk*32 + q*8);
            #pragma unroll
            for (int j = 0; j < 2; ++j) bf[j] = *(const short8*)(B + (wc*32 + j*16 + l15)*64 + kk*32 + q*8);
            #pragma unroll
            for (int i = 0; i < 2; ++i)
                #pragma unroll
                for (int j = 0; j < 2; ++j)
                    acc[i][j] = MFMA32(af[i], bf[j], acc[i][j], 0, 0, 0);
        }
    }

    #pragma unroll
    for (int i = 0; i < 2; ++i)
        #pragma unroll
        for (int r = 0; r < 4; ++r) {
            const int oc = r0 + wr*32 + i*16 + q*4 + r;
            const float bi = bp[oc];
            #pragma unroll
            for (int j = 0; j < 2; ++j) {
                const int n = c0 + wc*32 + j*16 + l15;
                out[((size_t)b*C + oc)*HW + n] = acc[i][j][r] + bi;
            }
        }
}

// ---------------------------------------------------------------------------
extern "C" void kernel_launch(void* const* d_in, const int* in_sizes, int n_in,
                              void* d_out, int out_size, void* d_ws, size_t ws_size,
                              hipStream_t stream) {
    const float* x  = (const float*)d_in[0];
    const float* wq = (const float*)d_in[1];
    const float* gq = (const float*)d_in[2];
    const float* bq = (const float*)d_in[3];
    const float* wk = (const float*)d_in[4];
    const float* gk = (const float*)d_in[5];
    const float* bk = (const float*)d_in[6];
    const float* wv = (const float*)d_in[7];
    const float* gv = (const float*)d_in[8];
    const float* bv = (const float*)d_in[9];
    const float* wp = (const float*)d_in[10];
    const float* gp = (const float*)d_in[11];
    const float* bp = (const float*)d_in[12];
    float* out = (float*)d_out;

    bf16u* qw = (bf16u*)d_ws;
    bf16u* kw = qw + (size_t)BB * MQ * HW;
    bf16u* vw = kw + (size_t)BB * MQ * HW;
    bf16u* xw = vw + (size_t)BB * DH * HW;
    bf16u* xTb = xw;
    bf16u* WcT = xw + (size_t)BB * MQ * HW;
    float* biasc = (float*)(WcT + 393216);
    bf16u* WpT = qw;                               // qT region, dead after attn

    hipLaunchKernelGGL(prepx, dim3(769), dim3(256), 0, stream,
                       wq, wk, wv, gq, bq, gk, bk, gv, bv, x, WcT, biasc, xTb);
    hipLaunchKernelGGL(qkv_gemm, dim3(12, 18, BB), dim3(256), 0, stream,
                       WcT, biasc, xTb, qw, kw, vw);
    hipLaunchKernelGGL(attn_mfma, dim3(18, NH, BB), dim3(256), 0, stream,
                       qw, kw, vw, xw);
    hipLaunchKernelGGL(prep2, dim3(128), dim3(256), 0, stream, wp, gp, WpT);
    hipLaunchKernelGGL(out_gemm, dim3(4, 36, BB), dim3(256), 0, stream,
                       WpT, bp, xw, out);
}

// Round 14
// 190.342 us; speedup vs baseline: 1.1405x; 1.0214x over previous
//
#include <hip/hip_runtime.h>

#define BB 4
#define C 256
#define HW 2304          // N = 48*48
#define NH 8
#define KD 32
#define D 128
#define DH 1024
#define MQ 256           // NH*KD

typedef unsigned short bf16u;
typedef __attribute__((ext_vector_type(8))) short short8;   // 8 bf16 (MFMA K=32 A/B frag)
typedef __attribute__((ext_vector_type(4))) float f32x4;    // MFMA C/D frag
typedef __attribute__((ext_vector_type(4))) unsigned ux4;
typedef __attribute__((ext_vector_type(2))) unsigned ux2;

union U8 { ux4 u; short8 s; };

__device__ __forceinline__ bf16u f2b(float f) {            // RNE
    unsigned u = __float_as_uint(f);
    return (bf16u)((u + 0x7fffu + ((u >> 16) & 1u)) >> 16);
}
// pack two fp32 -> dword of two bf16 (round-half-up): lo=a, hi=b. 3 VALU.
__device__ __forceinline__ unsigned pkb(float a, float b) {
    return __builtin_amdgcn_perm(__float_as_uint(b) + 0x8000u,
                                 __float_as_uint(a) + 0x8000u, 0x07060302u);
}

// async global->LDS, 16B/lane; lds base wave-uniform, dest = base + lane*16B
__device__ __forceinline__ void glds16(const bf16u* g, bf16u* l) {
    __builtin_amdgcn_global_load_lds(
        (const __attribute__((address_space(1))) unsigned int*)g,
        (__attribute__((address_space(3))) unsigned int*)l,
        16, 0, 0);
}

#define MFMA32 __builtin_amdgcn_mfma_f32_16x16x32_bf16

// ---------------------------------------------------------------------------
// Kernel 1: prepx — fused prep (QKV weights -> bf16 pre-tiled, BN folded,
// Q gets log2e; biasc) + xtrans (x [b][C][N] f32 -> xT [b][N][C] bf16).
// grid 769: blk<193 = prep, else xtrans.
// ---------------------------------------------------------------------------
__global__ __launch_bounds__(256) void prepx(
    const float* __restrict__ wq, const float* __restrict__ wk, const float* __restrict__ wv,
    const float* __restrict__ gq, const float* __restrict__ bq,
    const float* __restrict__ gk, const float* __restrict__ bk,
    const float* __restrict__ gv, const float* __restrict__ bv,
    const float* __restrict__ x,
    bf16u* __restrict__ WcT, float* __restrict__ biasc, bf16u* __restrict__ xT)
{
    __shared__ float tile[64][68];
    const float rs = rsqrtf(1.0f + 1e-5f);
    const float L2E = 1.4426950408889634f;
    const int t = threadIdx.x, blk = blockIdx.x;
    if (blk < 192) {
        const int idx = (blk*256 + t) * 8;
        const int row = idx >> 8;
        const int k   = idx & 255;
        const float* src; float sc;
        if (row < 256)      { src = wq + idx;            sc = gq[row]*rs*L2E; }
        else if (row < 512) { src = wk + (idx - 65536);  sc = gk[row-256]*rs; }
        else                { src = wv + (idx - 131072); sc = gv[row-512]*rs; }
        float4 a = *(const float4*)(src);
        float4 c = *(const float4*)(src + 4);
        ux4 v;
        v.x = pkb(a.x*sc, a.y*sc); v.y = pkb(a.z*sc, a.w*sc);
        v.z = pkb(c.x*sc, c.y*sc); v.w = pkb(c.z*sc, c.w*sc);
        const size_t dst = (size_t)((row>>7)*8 + (k>>5))*4096
                         + (size_t)((row&127)*4 + ((k&31)>>3))*8;
        *(ux4*)(WcT + dst) = v;
    } else if (blk == 192) {
        #pragma unroll
        for (int kk = 0; kk < 6; ++kk) {
            const int r = kk*256 + t;
            float v;
            if (r < 256)      v = bq[r] * L2E;
            else if (r < 512) v = bk[r - 256];
            else              v = bv[r - 512];
            biasc[r] = v;
        }
    } else {
        const int idx = blk - 193;                  // 576 xtrans blocks
        const int c0 = (idx & 3) * 64, n0 = ((idx >> 2) % 36) * 64, b = idx / 144;
        const float* xb = x + (size_t)b * C * HW;
        #pragma unroll
        for (int rr = 0; rr < 4; ++rr) {
            const int cl = rr*16 + (t >> 4);
            float4 v = *(const float4*)(xb + (size_t)(c0 + cl) * HW + n0 + (t & 15)*4);
            tile[cl][(t&15)*4+0] = v.x; tile[cl][(t&15)*4+1] = v.y;
            tile[cl][(t&15)*4+2] = v.z; tile[cl][(t&15)*4+3] = v.w;
        }
        __syncthreads();
        const int nl = t >> 2, ch = t & 3;
        short8 v0, v1;
        #pragma unroll
        for (int kk = 0; kk < 8; ++kk) v0[kk] = (short)f2b(tile[ch*16+kk][nl]);
        #pragma unroll
        for (int kk = 0; kk < 8; ++kk) v1[kk] = (short)f2b(tile[ch*16+8+kk][nl]);
        bf16u* dst = xT + ((size_t)b*HW + n0 + nl) * C + c0 + ch*16;
        *(short8*)(dst)     = v0;
        *(short8*)(dst + 8) = v1;
    }
}

// ---------------------------------------------------------------------------
// Kernel 2: QKV projection (R11, verified). A = pre-tiled bf16 weights,
// B = xT, both glds. 128x128, BK=32, triple-buffer prefetch-2, dense
// transposed epilogue; V written pi-permuted. grid (12,18,4), LDS 48KB.
// ---------------------------------------------------------------------------
__global__ __launch_bounds__(256, 3) void qkv_gemm(
    const bf16u* __restrict__ WcT, const float* __restrict__ biasc,
    const bf16u* __restrict__ xT,
    bf16u* __restrict__ qT, bf16u* __restrict__ kT, bf16u* __restrict__ vO)
{
    const int mt = blockIdx.x, ntb = blockIdx.y, b = blockIdx.z;
    const int r0 = mt * 128, c0 = ntb * 128;
    const int t = threadIdx.x, w = t >> 6, l = t & 63;
    const int l15 = l & 15, q = l >> 4;
    const int wr = w >> 1, wc = w & 1;

    __shared__ bf16u smem[24576];   // As: 0/4096/8192 | Bs: 12288/16384/20480

    const bf16u* xb = xT + (size_t)b * HW * C;

    const int sA0 = w*128 + l, sA1 = w*128 + 64 + l;        // 512 slots
    const bf16u* gA0 = WcT + (size_t)mt*32768 + (size_t)sA0*8;
    const bf16u* gA1 = WcT + (size_t)mt*32768 + (size_t)sA1*8;
    const bf16u* gB0 = xb + (size_t)(c0 + (sA0>>2)) * C + (sA0&3)*8;
    const bf16u* gB1 = xb + (size_t)(c0 + (sA1>>2)) * C + (sA1&3)*8;

    f32x4 acc[4][4];
    #pragma unroll
    for (int i = 0; i < 4; ++i)
        #pragma unroll
        for (int j = 0; j < 4; ++j) { acc[i][j][0]=0.f; acc[i][j][1]=0.f; acc[i][j][2]=0.f; acc[i][j][3]=0.f; }

    auto stage = [&](int it2, int bb) {
        bf16u* As = smem + bb*4096;
        bf16u* Bs = smem + 12288 + bb*4096;
        glds16(gA0 + it2*4096, As + sA0*8);
        glds16(gA1 + it2*4096, As + sA1*8);
        glds16(gB0 + it2*32,   Bs + sA0*8);
        glds16(gB1 + it2*32,   Bs + sA1*8);
    };

    const bool isV = (r0 >= 512);
    stage(0, 0); stage(1, 1);
    for (int it = 0; it < 8; ++it) {
        __syncthreads();
        if (it + 2 < 8) stage(it + 2, (it + 2) % 3);
        const bf16u* A = smem + (it % 3) * 4096;
        const bf16u* B = smem + 12288 + (it % 3) * 4096;
        short8 af[4], bf[4];
        #pragma unroll
        for (int i = 0; i < 4; ++i) af[i] = *(const short8*)(A + (wr*64 + i*16 + l15)*32 + q*8);
        #pragma unroll
        for (int j = 0; j < 4; ++j) bf[j] = *(const short8*)(B + (wc*64 + j*16 + l15)*32 + q*8);
        if (!isV) {
            #pragma unroll
            for (int i = 0; i < 4; ++i)
                #pragma unroll
                for (int j = 0; j < 4; ++j)
                    acc[i][j] = MFMA32(af[i], bf[j], acc[i][j], 0, 0, 0);
        } else {   // C^T: D[row=n][col=oc]
            #pragma unroll
            for (int i = 0; i < 4; ++i)
                #pragma unroll
                for (int j = 0; j < 4; ++j)
                    acc[i][j] = MFMA32(bf[j], af[i], acc[i][j], 0, 0, 0);
        }
    }

    __syncthreads();
    bf16u* Od = smem + w * 4608;          // per-wave [64][72]

    if (!isV) {
        float bC[4][4];
        #pragma unroll
        for (int i = 0; i < 4; ++i)
            #pragma unroll
            for (int r = 0; r < 4; ++r)
                bC[i][r] = biasc[r0 + wr*64 + i*16 + q*4 + r];
        #pragma unroll
        for (int i = 0; i < 4; ++i)
            #pragma unroll
            for (int j = 0; j < 4; ++j) {
                float y0 = acc[i][j][0] + bC[i][0];
                float y1 = acc[i][j][1] + bC[i][1];
                float y2 = acc[i][j][2] + bC[i][2];
                float y3 = acc[i][j][3] + bC[i][3];
                ux2 pk; pk.x = pkb(y0, y1); pk.y = pkb(y2, y3);
                *(ux2*)(Od + (j*16 + l15)*72 + i*16 + q*4) = pk;
            }
        bf16u* dst = (r0 < 256) ? qT : kT;
        #pragma unroll
        for (int hh = 0; hh < 2; ++hh) {
            const int h = ((r0 & 255) + wr*64 + hh*32) >> 5;
            bf16u* dh_ = dst + (size_t)(b*NH + h) * HW * KD;
            #pragma unroll
            for (int rg = 0; rg < 4; ++rg) {
                const int row = rg*16 + (l >> 2);
                const int n = c0 + wc*64 + row;
                short8 v = *(const short8*)(Od + row*72 + hh*32 + (l & 3)*8);
                *(short8*)(dh_ + (size_t)n * KD + (l & 3)*8) = v;
            }
        }
    } else {
        float bC[4];
        #pragma unroll
        for (int i = 0; i < 4; ++i)
            bC[i] = biasc[r0 + wr*64 + i*16 + l15];
        #pragma unroll
        for (int i = 0; i < 4; ++i)
            #pragma unroll
            for (int j = 0; j < 4; ++j) {
                float y0 = acc[i][j][0] + bC[i];
                float y1 = acc[i][j][1] + bC[i];
                float y2 = acc[i][j][2] + bC[i];
                float y3 = acc[i][j][3] + bC[i];
                ux2 pk; pk.x = pkb(y0, y1); pk.y = pkb(y2, y3);
                const int p = (j >> 1)*32 + q*8 + (j & 1)*4;
                *(ux2*)(Od + (i*16 + l15)*72 + p) = pk;
            }
        bf16u* dst = vO + (size_t)b * DH * HW;
        #pragma unroll
        for (int it2 = 0; it2 < 8; ++it2) {
            const int row = it2*8 + (l >> 3);
            const int d = (r0 - 512) + wr*64 + row;
            short8 v = *(const short8*)(Od + row*72 + (l & 7)*8);
            *(short8*)(dst + (size_t)d * HW + c0 + wc*64 + (l & 7)*8) = v;
        }
    }
}

// ---------------------------------------------------------------------------
// Kernel 3: MFMA flash attention — balanced grid. Block = 96 queries,
// 2 waves x 48 q (o[3][8] = 96 acc VGPRs). Grid (24,8,4) = 768 = EXACTLY
// 3 blocks/CU (R13's 2.25 had a 3-vs-2 tail pacing +33%). Each V b128 LDS
// read feeds 3 MFMAs (grid V-read volume x0.67). K frags direct from global,
// reloaded in place right after the S^T MFMAs consume them (saves the kfn
// double-buffer's 32 VGPRs; latency covered by exp+PV+barrier). MFMA row
// sums (P.ones). Zero-movement P A-frags (pi-permuted k); V glds permuted+
// swizzled (conflict-free b128); no-max softmax (exp2, log2e pre-folded).
// LDS 32 KB (Vs dbuf; Od aliased in epilogue).
// ---------------------------------------------------------------------------
__global__ __launch_bounds__(128, 2) void attn_mfma(
    const bf16u* __restrict__ qT, const bf16u* __restrict__ kT,
    const bf16u* __restrict__ vg, bf16u* __restrict__ xg)
{
    const int nt = blockIdx.x, h = blockIdx.y, b = blockIdx.z;
    const int n0 = nt * 96;
    const int t = threadIdx.x;
    const int w = t >> 6, l = t & 63, l15 = l & 15, q = l >> 4;

    const bf16u* qTh = qT + (size_t)(b*NH + h) * HW * KD;
    const bf16u* kTh = kT + (size_t)(b*NH + h) * HW * KD;
    const bf16u* vh  = vg + ((size_t)b*DH + (size_t)h*D) * HW;

    __shared__ bf16u smem[16384];   // Vs dbuf 2x8192 els (32KB); Od alias

    short8 qf[3];
    #pragma unroll
    for (int g = 0; g < 3; ++g)
        qf[g] = *(const short8*)(qTh + (size_t)(n0 + w*48 + g*16 + l15) * KD + q*8);

    const short8 ones = { (short)0x3F80, (short)0x3F80, (short)0x3F80, (short)0x3F80,
                          (short)0x3F80, (short)0x3F80, (short)0x3F80, (short)0x3F80 };

    f32x4 o[3][8];
    #pragma unroll
    for (int g = 0; g < 3; ++g)
        #pragma unroll
        for (int d = 0; d < 8; ++d) { o[g][d][0]=0.f; o[g][d][1]=0.f; o[g][d][2]=0.f; o[g][d][3]=0.f; }
    f32x4 os[3];
    #pragma unroll
    for (int g = 0; g < 3; ++g) { os[g][0]=0.f; os[g][1]=0.f; os[g][2]=0.f; os[g][3]=0.f; }
    const f32x4 zero = {0.f, 0.f, 0.f, 0.f};

    auto stageV = [&](int m0, int bb) {
        bf16u* Vs = smem + bb*8192;
        #pragma unroll
        for (int j = 0; j < 8; ++j) {
            const int s = (w*8 + j)*64 + l;       // 1024 slots of 16B
            const int d = s >> 3, c = s & 7, cg = c ^ (d & 7);
            glds16(vh + (size_t)d*HW + m0 + cg*8, Vs + (w*8 + j)*512);
        }
    };

    // K frag prefetch (tile 0); reloaded in place each iteration
    short8 kfc[4];
    #pragma unroll
    for (int kt = 0; kt < 4; ++kt)
        kfc[kt] = *(const short8*)(kTh + (size_t)(kt*16 + l15) * KD + q*8);
    stageV(0, 0);

    for (int mt = 0; mt < 36; ++mt) {
        __syncthreads();
        if (mt < 35) stageV((mt+1)*64, (mt+1)&1);
        const bf16u* Vs = smem + (mt&1)*8192;

        // --- S^T + exp2 + pack, per query group (caps register liveness) ---
        unsigned dA[3][4], dB[3][4];
        #pragma unroll
        for (int g = 0; g < 3; ++g) {
            f32x4 st[4];
            #pragma unroll
            for (int kt = 0; kt < 4; ++kt)
                st[kt] = MFMA32(kfc[kt], qf[g], zero, 0, 0, 0);
            #pragma unroll
            for (int kt = 0; kt < 4; ++kt) {
                float p0 = __builtin_amdgcn_exp2f(st[kt][0]);
                float p1 = __builtin_amdgcn_exp2f(st[kt][1]);
                float p2 = __builtin_amdgcn_exp2f(st[kt][2]);
                float p3 = __builtin_amdgcn_exp2f(st[kt][3]);
                dA[g][kt] = pkb(p0, p1); dB[g][kt] = pkb(p2, p3);
            }
        }

        // --- reload K frags for next tile (kfc free after S^T) ---
        if (mt < 35) {
            #pragma unroll
            for (int kt = 0; kt < 4; ++kt)
                kfc[kt] = *(const short8*)(kTh + (size_t)((mt+1)*64 + kt*16 + l15) * KD + q*8);
        }

        // --- PV + row sums: zero-movement A-frags; B = b128 (permuted V) ---
        #pragma unroll
        for (int kh = 0; kh < 2; ++kh) {
            U8 u[3];
            #pragma unroll
            for (int g = 0; g < 3; ++g) {
                u[g].u[0] = dA[g][kh*2];   u[g].u[1] = dB[g][kh*2];
                u[g].u[2] = dA[g][kh*2+1]; u[g].u[3] = dB[g][kh*2+1];
            }
            #pragma unroll
            for (int dt = 0; dt < 8; ++dt) {
                const int d = dt*16 + l15;
                short8 vf = *(const short8*)(Vs + d*64 + (((kh*4 + q) ^ (d & 7)) * 8));
                #pragma unroll
                for (int g = 0; g < 3; ++g)
                    o[g][dt] = MFMA32(u[g].s, vf, o[g][dt], 0, 0, 0);
            }
            #pragma unroll
            for (int g = 0; g < 3; ++g)
                os[g] = MFMA32(u[g].s, ones, os[g], 0, 0, 0);
        }
    }

    // --- epilogue: /l + ReLU, LDS transpose, dense [n][DH] store ---
    float inv[3][4];
    #pragma unroll
    for (int g = 0; g < 3; ++g)
        #pragma unroll
        for (int r = 0; r < 4; ++r)
            inv[g][r] = 1.0f / os[g][r];      // lane reg r = sum for query q*4+r
    __syncthreads();
    bf16u* Od = smem + w * 6528;        // per-wave [48][136]
    #pragma unroll
    for (int g = 0; g < 3; ++g)
        #pragma unroll
        for (int dt = 0; dt < 8; ++dt)
            #pragma unroll
            for (int r = 0; r < 4; ++r) {
                float v = fmaxf(o[g][dt][r] * inv[g][r], 0.f);
                Od[(g*16 + q*4 + r)*136 + dt*16 + l15] = f2b(v);
            }
    // dense: 8 lanes cover 128B of one n row; 8 rows/instr; 12 instrs
    bf16u* xb = xg + ((size_t)b*HW + n0 + w*48) * DH + h*D;
    #pragma unroll
    for (int it = 0; it < 6; ++it) {
        const int row = it*8 + (l >> 3);
        #pragma unroll
        for (int hf = 0; hf < 2; ++hf) {
            const int ch = hf*8 + (l & 7);
            *(short8*)(xb + (size_t)row*DH + ch*8) =
                *(const short8*)(Od + row*136 + ch*8);
        }
    }
}

// ---------------------------------------------------------------------------
// Kernel 3.5: prep2 — wp fp32 -> bf16 (gp*rs folded), tiled for DIRECT
// lane-linear A-frag loads: tile (row-block 16, k-block 32) of 512 els at
// ((row>>4)*32 + (k>>5))*512; within, element (r, q*8+j) at (q*16+r)*8+j.
// grid 128.
// ---------------------------------------------------------------------------
__global__ __launch_bounds__(256) void prep2(
    const float* __restrict__ wp, const float* __restrict__ gp,
    bf16u* __restrict__ WpT)
{
    const float rs = rsqrtf(1.0f + 1e-5f);
    const int item = blockIdx.x*256 + threadIdx.x;
    const int row = item >> 7;
    const int k   = (item & 127) * 8;
    const float sc = gp[row] * rs;
    const float* src = wp + (size_t)row*DH + k;
    float4 a = *(const float4*)(src);
    float4 c = *(const float4*)(src + 4);
    ux4 v;
    v.x = pkb(a.x*sc, a.y*sc); v.y = pkb(a.z*sc, a.w*sc);
    v.z = pkb(c.x*sc, c.y*sc); v.w = pkb(c.z*sc, c.w*sc);
    const size_t dst = (size_t)((row>>4)*32 + (k>>5))*512
                     + (size_t)(((k>>3)&3)*16 + (row&15))*8;
    *(ux4*)(WpT + dst) = v;
}

// ---------------------------------------------------------------------------
// Kernel 4: out = wp' @ xx + bp (gp*rs pre-folded). 64x64, BK=64, 16 iters.
// A-frags DIRECT from global (lane-linear 1KB/wave, L2-resident 0.5MB) —
// no A staging; LDS = Bs triple-buffer only (24KB). fp32 out. grid (4,36,4).
// ---------------------------------------------------------------------------
__global__ __launch_bounds__(256, 3) void out_gemm(
    const bf16u* __restrict__ WpT, const float* __restrict__ bp,
    const bf16u* __restrict__ xx, float* __restrict__ out)
{
    const int mt = blockIdx.x, ntb = blockIdx.y, b = blockIdx.z;
    const int r0 = mt * 64, c0 = ntb * 64;
    const int t = threadIdx.x, w = t >> 6, l = t & 63;
    const int l15 = l & 15, q = l >> 4;
    const int wr = w >> 1, wc = w & 1;

    __shared__ bf16u smem[12288];   // Bs: 0/4096/8192

    const bf16u* xb = xx + (size_t)b * HW * DH;

    const int sB0 = w*128 + l, sB1 = w*128 + 64 + l;
    const bf16u* gB0 = xb + (size_t)(c0 + (sB0>>3)) * DH + (sB0&7)*8;
    const bf16u* gB1 = xb + (size_t)(c0 + (sB1>>3)) * DH + (sB1&7)*8;
    const bf16u* gA  = WpT + (size_t)(mt*4 + wr*2)*32*512 + (size_t)l*8;

    f32x4 acc[2][2];
    #pragma unroll
    for (int i = 0; i < 2; ++i)
        #pragma unroll
        for (int j = 0; j < 2; ++j) { acc[i][j][0]=0.f; acc[i][j][1]=0.f; acc[i][j][2]=0.f; acc[i][j][3]=0.f; }

    auto stage = [&](int it2, int bb) {
        bf16u* Bs = smem + bb*4096;
        glds16(gB0 + it2*64, Bs + sB0*8);
        glds16(gB1 + it2*64, Bs + sB1*8);
    };

    stage(0, 0); stage(1, 1);
    for (int it = 0; it < 16; ++it) {
        __syncthreads();
        if (it + 2 < 16) stage(it + 2, (it + 2) % 3);
        const bf16u* B = smem + (it % 3) * 4096;
        #pragma unroll
        for (int kk = 0; kk < 2; ++kk) {
            short8 af[2], bf[2];
            #pragma unroll
            for (int i = 0; i < 2; ++i)
                af[i] = *(const short8*)(gA + (size_t)(i*32 + it*2 + kk)*512);
            #pragma unroll
            for (int j = 0; j < 2; ++j)
                bf[j] = *(const short8*)(B + (wc*32 + j*16 + l15)*64 + kk*32 + q*8);
            #pragma unroll
            for (int i = 0; i < 2; ++i)
                #pragma unroll
                for (int j = 0; j < 2; ++j)
                    acc[i][j] = MFMA32(af[i], bf[j], acc[i][j], 0, 0, 0);
        }
    }

    #pragma unroll
    for (int i = 0; i < 2; ++i)
        #pragma unroll
        for (int r = 0; r < 4; ++r) {
            const int oc = r0 + wr*32 + i*16 + q*4 + r;
            const float bi = bp[oc];
            #pragma unroll
            for (int j = 0; j < 2; ++j) {
                const int n = c0 + wc*32 + j*16 + l15;
                out[((size_t)b*C + oc)*HW + n] = acc[i][j][r] + bi;
            }
        }
}

// ---------------------------------------------------------------------------
extern "C" void kernel_launch(void* const* d_in, const int* in_sizes, int n_in,
                              void* d_out, int out_size, void* d_ws, size_t ws_size,
                              hipStream_t stream) {
    const float* x  = (const float*)d_in[0];
    const float* wq = (const float*)d_in[1];
    const float* gq = (const float*)d_in[2];
    const float* bq = (const float*)d_in[3];
    const float* wk = (const float*)d_in[4];
    const float* gk = (const float*)d_in[5];
    const float* bk = (const float*)d_in[6];
    const float* wv = (const float*)d_in[7];
    const float* gv = (const float*)d_in[8];
    const float* bv = (const float*)d_in[9];
    const float* wp = (const float*)d_in[10];
    const float* gp = (const float*)d_in[11];
    const float* bp = (const float*)d_in[12];
    float* out = (float*)d_out;

    bf16u* qw = (bf16u*)d_ws;
    bf16u* kw = qw + (size_t)BB * MQ * HW;
    bf16u* vw = kw + (size_t)BB * MQ * HW;
    bf16u* xw = vw + (size_t)BB * DH * HW;
    bf16u* xTb = xw;
    bf16u* WcT = xw + (size_t)BB * MQ * HW;
    float* biasc = (float*)(WcT + 393216);
    bf16u* WpT = qw;                               // qT region, dead after attn

    hipLaunchKernelGGL(prepx, dim3(769), dim3(256), 0, stream,
                       wq, wk, wv, gq, bq, gk, bk, gv, bv, x, WcT, biasc, xTb);
    hipLaunchKernelGGL(qkv_gemm, dim3(12, 18, BB), dim3(256), 0, stream,
                       WcT, biasc, xTb, qw, kw, vw);
    hipLaunchKernelGGL(attn_mfma, dim3(24, NH, BB), dim3(128), 0, stream,
                       qw, kw, vw, xw);
    hipLaunchKernelGGL(prep2, dim3(128), dim3(256), 0, stream, wp, gp, WpT);
    hipLaunchKernelGGL(out_gemm, dim3(4, 36, BB), dim3(256), 0, stream,
                       WpT, bp, xw, out);
}